// Round 5
// baseline (540.700 us; speedup 1.0000x reference)
//
#include <hip/hip_runtime.h>
#include <stdint.h>

// Problem constants (match the reference).
#define B 256
#define K 64
#define L 32
#define SENTINEL 32u
#define NUM_SLOTS 100000
#define HALF 64

// R9: fill-shaped expand. R8's expand ran at ~3 TB/s (vs the harness fill's
// 6.2 TB/s with the SAME full-line store coverage). Remaining structural
// difference was work granularity: R8 blocks did 16 KB each (cold 64 B codes
// load -> barrier -> 16 store instrs -> retire) x 32768 blocks, so per-block
// startup latency ~= per-block store time. Now: 2048 long-lived blocks
// (8/CU), each owns a contiguous 256 KB output span (512 rows), stages its
// 1 KB of codes into LDS once, then issues 64 back-to-back 1 KB-per-wave
// store iterations. Stores are nontemporal (output is never re-read;
// no-allocate skips L2 dirty-line churn, matching fillBuffer's FETCH~0).
// Resolve kernel unchanged from R8 (isolates the expand-phase variable).

#define HASH_SIZE 4096
#define HASH_MASK 4095u
#define RESOLVE_THREADS 1024
#define EPB (2 * K * L)                 // elements (rows) per batch = 4096
#define ROWS (2 * B * K * L)            // 1,048,576 output rows
#define EXP_BLOCKS 2048
#define EXP_THREADS 256
#define ROWS_PER_EBLOCK (ROWS / EXP_BLOCKS)   // 512 rows = 256 KB out / block

typedef float fvec4 __attribute__((ext_vector_type(4)));

// ---------------------------------------------------------------------------
// Kernel 1: per-batch LDS hash build + per-element resolve -> u16 codes.
// code = pown | pcross<<6 ; 0xFFFF = invalid row (emit zeros downstream).
// ---------------------------------------------------------------------------
__global__ __launch_bounds__(RESOLVE_THREADS) void wpe_resolve_kernel(
    const int* __restrict__ src_walks,
    const int* __restrict__ tgt_walks,
    const int* __restrict__ src_lens,
    const int* __restrict__ tgt_lens,
    unsigned short* __restrict__ codes) {
  __shared__ int            s_keys[HASH_SIZE];
  __shared__ unsigned int   s_vsrc[HASH_SIZE];
  __shared__ unsigned int   s_vtgt[HASH_SIZE];
  __shared__ unsigned short s_slot[EPB];
  __shared__ int            s_lens[2 * K];

  const unsigned int b = blockIdx.x;
  const unsigned int t = threadIdx.x;
  const unsigned int base = b * (K * L);

  // ---- Phase 0: init hash + stage lens ----
  for (unsigned int i = t; i < HASH_SIZE; i += RESOLVE_THREADS) {
    s_keys[i] = 0;
    s_vsrc[i] = SENTINEL;
    s_vtgt[i] = SENTINEL;
  }
  if (t < 2 * K) {
    s_lens[t] = (t < K) ? src_lens[b * K + t] : tgt_lens[b * K + (t - K)];
  }
  __syncthreads();

  // ---- Phase 1: scatter-min into hash, recording each element's slot ----
  for (unsigned int e = t; e < EPB; e += RESOLVE_THREADS) {
    unsigned int which = e >> 11;
    unsigned int idx   = e & 2047u;
    unsigned int l     = idx & (L - 1);
    unsigned int k     = idx >> 5;
    const int* walks = which ? tgt_walks : src_walks;
    int node = walks[base + idx];
    int len  = s_lens[which * K + k];
    unsigned short slot = 0xFFFFu;
    if ((int)l < len && node != 0) {
      unsigned int h = ((unsigned int)node * 0x9E3779B1u) >> 20;  // top 12 bits
      while (true) {
        int prev = atomicCAS(&s_keys[h], 0, node);
        if (prev == 0 || prev == node) break;
        h = (h + 1) & HASH_MASK;
      }
      if (which) atomicMin(&s_vtgt[h], l);
      else       atomicMin(&s_vsrc[h], l);
      slot = (unsigned short)h;
    }
    s_slot[e] = slot;
  }
  __syncthreads();

  // ---- Phase 2: direct slot lookup -> packed u16 code ----
  for (unsigned int e = t; e < EPB; e += RESOLVE_THREADS) {
    unsigned int which = e >> 11;
    unsigned int slot  = s_slot[e];
    unsigned short code = 0xFFFFu;
    if (slot != 0xFFFFu) {
      unsigned int ps = s_vsrc[slot];
      unsigned int pt = s_vtgt[slot];
      unsigned int pown   = which ? pt : ps;
      unsigned int pcross = which ? ps : pt;
      code = (unsigned short)(pown | (pcross << 6));
    }
    codes[b * (unsigned)(K * L) + which * (unsigned)(B * K * L) + (e & 2047u)] = code;
  }
}

// ---------------------------------------------------------------------------
// Kernel 2: fill-shaped expand. Block owns rows [blockIdx*512, +512) =
// 256 KB of contiguous output. Codes staged to LDS once (coalesced u32).
// Iteration it: entry = entryBase + it*256 + t -> each wave stores 1 KB
// fully contiguous, nontemporal. Gathers are L1-resident (two 8.4 KB tables).
// ---------------------------------------------------------------------------
__global__ __launch_bounds__(EXP_THREADS) void wpe_expand_kernel(
    const unsigned short* __restrict__ codes,
    const float* __restrict__ own_emb,
    const float* __restrict__ cross_emb,
    fvec4* __restrict__ out) {
  __shared__ unsigned short s_code[ROWS_PER_EBLOCK];

  const unsigned int t = threadIdx.x;
  const unsigned int rowBase = blockIdx.x * (unsigned)ROWS_PER_EBLOCK;

  // Stage this block's 512 codes (1 KB) via coalesced u32 loads.
  ((unsigned int*)s_code)[t] =
      ((const unsigned int*)codes)[(rowBase >> 1) + t];
  __syncthreads();

  const fvec4* own4   = (const fvec4*)own_emb;    // [33][16]
  const fvec4* cross4 = (const fvec4*)cross_emb;  // [33][16]

  const unsigned int entryBase = rowBase * 32u;   // fvec4 index (max 2^25, fits)

#pragma unroll 8
  for (unsigned int it = 0; it < (ROWS_PER_EBLOCK * 32u) / EXP_THREADS; ++it) {
    unsigned int lid = it * EXP_THREADS + t;  // 0..16383 within block span
    unsigned int lr  = lid >> 5;              // local row 0..511
    unsigned int col = lid & 31u;             // fvec4 column within row

    unsigned int code = s_code[lr];           // broadcast per 32-lane group
    fvec4 v = (fvec4)(0.f, 0.f, 0.f, 0.f);
    if (code != 0xFFFFu) {
      unsigned int pown   = code & 63u;
      unsigned int pcross = (code >> 6) & 63u;
      const fvec4* p = (col < 16u) ? (own4   + pown   * 16u + col)
                                   : (cross4 + pcross * 16u + (col - 16u));
      v = *p;
    }
    __builtin_nontemporal_store(v, &out[entryBase + lid]);
  }
}

// ---------------------------------------------------------------------------
extern "C" void kernel_launch(void* const* d_in, const int* in_sizes, int n_in,
                              void* d_out, int out_size, void* d_ws, size_t ws_size,
                              hipStream_t stream) {
  const int*   src_walks = (const int*)d_in[0];
  const int*   tgt_walks = (const int*)d_in[1];
  const int*   src_lens  = (const int*)d_in[2];
  const int*   tgt_lens  = (const int*)d_in[3];
  const float* own_emb   = (const float*)d_in[4];
  const float* cross_emb = (const float*)d_in[5];

  unsigned short* codes = (unsigned short*)d_ws;  // 2 MB

  // Step 1: per-batch hash build + element resolve (thin grid, LDS-heavy).
  wpe_resolve_kernel<<<B, RESOLVE_THREADS, 0, stream>>>(
      src_walks, tgt_walks, src_lens, tgt_lens, codes);

  // Step 2: fill-shaped streaming expand (long-lived blocks, NT stores).
  wpe_expand_kernel<<<EXP_BLOCKS, EXP_THREADS, 0, stream>>>(
      codes, own_emb, cross_emb, (fvec4*)d_out);
}

// Round 6
// 534.321 us; speedup vs baseline: 1.0119x; 1.0119x over previous
//
#include <hip/hip_runtime.h>
#include <stdint.h>

// Problem constants (match the reference).
#define B 256
#define K 64
#define L 32
#define SENTINEL 32u
#define NUM_SLOTS 100000
#define HALF 64

// R10: revert R9's NT/fill-shaped expand to the best-measured R8 expand
// (537.1 us), and vectorize resolve phase-1 walk loads as int4.
//
// Session model (fits R5-R9 with zero free parameters): timed window =
// ~345 us 2 GiB arena poison fill + ~90 us output poison fill (invisible:
// below the top-5 cutoff) + our kernels. Our work per round: R5 118, R6 105,
// R7 130, R8 102, R9 106 us. Expand has been at ~92 us ~= 5.8 TB/s (within
// 7% of the fill's 6.2 TB/s) in every variant -- store-side changes were
// null because the store side was never the problem. Remaining non-roofline
// piece is resolve (~10 us): phase 1 now does one int4 walk load + one len
// read per thread (4 elements) instead of 4 scalar loads.

#define HASH_SIZE 4096
#define HASH_MASK 4095u
#define RESOLVE_THREADS 1024
#define EPB (2 * K * L)                 // elements (rows) per batch = 4096
#define ROWS (2 * B * K * L)            // 1,048,576 output rows

typedef float fvec4 __attribute__((ext_vector_type(4)));

// ---------------------------------------------------------------------------
// Kernel 1: per-batch LDS hash build + per-element resolve -> u16 codes.
// code = pown | pcross<<6 ; 0xFFFF = invalid row (emit zeros downstream).
// ---------------------------------------------------------------------------
__global__ __launch_bounds__(RESOLVE_THREADS) void wpe_resolve_kernel(
    const int* __restrict__ src_walks,
    const int* __restrict__ tgt_walks,
    const int* __restrict__ src_lens,
    const int* __restrict__ tgt_lens,
    unsigned short* __restrict__ codes) {
  __shared__ int            s_keys[HASH_SIZE];
  __shared__ unsigned int   s_vsrc[HASH_SIZE];
  __shared__ unsigned int   s_vtgt[HASH_SIZE];
  __shared__ unsigned short s_slot[EPB];
  __shared__ int            s_lens[2 * K];

  const unsigned int b = blockIdx.x;
  const unsigned int t = threadIdx.x;
  const unsigned int base = b * (K * L);

  // ---- Phase 0: init hash + stage lens ----
  for (unsigned int i = t; i < HASH_SIZE; i += RESOLVE_THREADS) {
    s_keys[i] = 0;
    s_vsrc[i] = SENTINEL;
    s_vtgt[i] = SENTINEL;
  }
  if (t < 2 * K) {
    s_lens[t] = (t < K) ? src_lens[b * K + t] : tgt_lens[b * K + (t - K)];
  }
  __syncthreads();

  // ---- Phase 1: scatter-min into hash (int4: 4 consecutive l per thread) --
  // e0 = t*4: which = t>>9, idx0 = (t&511)*4, l0 = (t&7)*4, k = (t&511)>>3.
  {
    unsigned int which = t >> 9;
    unsigned int q     = t & 511u;           // int4 index within batch half
    unsigned int l0    = (t & 7u) * 4u;
    unsigned int k     = q >> 3;
    const int* walks = which ? tgt_walks : src_walks;
    int4 nodes = ((const int4*)(walks + base))[q];
    int len = s_lens[which * K + k];
    int narr[4] = {nodes.x, nodes.y, nodes.z, nodes.w};
    unsigned int e0 = t * 4u;
#pragma unroll
    for (int j = 0; j < 4; ++j) {
      unsigned int l = l0 + (unsigned)j;
      int node = narr[j];
      unsigned short slot = 0xFFFFu;
      if ((int)l < len && node != 0) {
        unsigned int h = ((unsigned int)node * 0x9E3779B1u) >> 20;  // top 12b
        while (true) {
          int prev = atomicCAS(&s_keys[h], 0, node);
          if (prev == 0 || prev == node) break;
          h = (h + 1) & HASH_MASK;
        }
        if (which) atomicMin(&s_vtgt[h], l);
        else       atomicMin(&s_vsrc[h], l);
        slot = (unsigned short)h;
      }
      s_slot[e0 + (unsigned)j] = slot;
    }
  }
  __syncthreads();

  // ---- Phase 2: direct slot lookup -> packed u16 code ----
  for (unsigned int e = t; e < EPB; e += RESOLVE_THREADS) {
    unsigned int which = e >> 11;
    unsigned int slot  = s_slot[e];
    unsigned short code = 0xFFFFu;
    if (slot != 0xFFFFu) {
      unsigned int ps = s_vsrc[slot];
      unsigned int pt = s_vtgt[slot];
      unsigned int pown   = which ? pt : ps;
      unsigned int pcross = which ? ps : pt;
      code = (unsigned short)(pown | (pcross << 6));
    }
    codes[b * (unsigned)(K * L) + which * (unsigned)(B * K * L) + (e & 2047u)] = code;
  }
}

// ---------------------------------------------------------------------------
// Kernel 2: expand codes -> embeddings (best-measured R8 variant, plain
// stores). Block of 256 threads covers 1024 consecutive fvec4 entries =
// 32 rows. Each wave stores 1 KB fully contiguous; gathers are L1-resident.
// ---------------------------------------------------------------------------
__global__ __launch_bounds__(256) void wpe_expand_kernel(
    const unsigned short* __restrict__ codes,
    const float* __restrict__ own_emb,
    const float* __restrict__ cross_emb,
    fvec4* __restrict__ out) {
  __shared__ unsigned short s_code[32];

  const unsigned int t = threadIdx.x;
  const unsigned int rowBase = blockIdx.x * 32u;          // 32 rows per block
  const unsigned int entryBase = blockIdx.x * 1024u;

  if (t < 32u) s_code[t] = codes[rowBase + t];
  __syncthreads();

  const fvec4* own4   = (const fvec4*)own_emb;    // [33][16]
  const fvec4* cross4 = (const fvec4*)cross_emb;  // [33][16]

#pragma unroll
  for (unsigned int it = 0; it < 4; ++it) {
    unsigned int lid = it * 256u + t;        // 0..1023 within block
    unsigned int lr  = lid >> 5;             // local row 0..31
    unsigned int col = lid & 31u;            // fvec4 column within row

    unsigned int code = s_code[lr];
    fvec4 v = (fvec4)(0.f, 0.f, 0.f, 0.f);
    if (code != 0xFFFFu) {
      unsigned int pown   = code & 63u;
      unsigned int pcross = (code >> 6) & 63u;
      const fvec4* p = (col < 16u) ? (own4   + pown   * 16u + col)
                                   : (cross4 + pcross * 16u + (col - 16u));
      v = *p;
    }
    out[entryBase + lid] = v;
  }
}

// ---------------------------------------------------------------------------
extern "C" void kernel_launch(void* const* d_in, const int* in_sizes, int n_in,
                              void* d_out, int out_size, void* d_ws, size_t ws_size,
                              hipStream_t stream) {
  const int*   src_walks = (const int*)d_in[0];
  const int*   tgt_walks = (const int*)d_in[1];
  const int*   src_lens  = (const int*)d_in[2];
  const int*   tgt_lens  = (const int*)d_in[3];
  const float* own_emb   = (const float*)d_in[4];
  const float* cross_emb = (const float*)d_in[5];

  unsigned short* codes = (unsigned short*)d_ws;  // 2 MB

  // Step 1: per-batch hash build + element resolve (thin grid, LDS-heavy).
  wpe_resolve_kernel<<<B, RESOLVE_THREADS, 0, stream>>>(
      src_walks, tgt_walks, src_lens, tgt_lens, codes);

  // Step 2: streaming expand, wave-contiguous 1 KB stores (R8 variant).
  {
    const unsigned int blocks = ROWS / 32u;  // 32,768 blocks x 256 threads
    wpe_expand_kernel<<<blocks, 256, 0, stream>>>(
        codes, own_emb, cross_emb, (fvec4*)d_out);
  }
}